// Round 8
// baseline (68.592 us; speedup 1.0000x reference)
//
#include <hip/hip_runtime.h>
#include <cfloat>
#include <math.h>
#include <stdint.h>

// Match XLA-CPU f32 arithmetic exactly: no implicit contraction anywhere;
// FMA only where written explicitly (Eigen-gemm-style cross product).
#pragma clang fp contract(off)

#define RPW 16    // receivers per block (quarter of B=64)
#define NQ  256   // tile phases; grid = 4*NQ = 1024 (r3 geometry: best. r5/r6
                  // showed bigger grids enlarge L2 working set and regress.)

__device__ __forceinline__ uint32_t monotone_key(float f) {
    uint32_t u = __float_as_uint(f);
    return (u & 0x80000000u) ? ~u : (u | 0x80000000u);
}

// force a wave-uniform float into an SGPR
__device__ __forceinline__ float rfl_f(float x) {
    return __uint_as_float((uint32_t)__builtin_amdgcn_readfirstlane((int)__float_as_uint(x)));
}

__device__ __forceinline__ unsigned long long shfl_xor_u64(unsigned long long v, int m) {
    uint32_t lo = (uint32_t)v, hi = (uint32_t)(v >> 32);
    lo = (uint32_t)__shfl_xor((int)lo, m, 64);
    hi = (uint32_t)__shfl_xor((int)hi, m, 64);
    return ((unsigned long long)hi << 32) | lo;
}

// lane = point; 16 receivers in SGPRs -> pure-VALU inner loop.
// Min-fold: per (tile, receiver) fold the lane's 4 d2 via v_min (value only),
// track the winning GROUP (p0>>2) with one strict compare; exact index is
// recovered in finalize by re-evaluating the 4-point group bit-identically.
// Group ordering argument: groups partition index space ascending with p0,
// so the lowest-p0 group attaining the global min d2 contains the reference's
// first-occurrence argmin; u64 min on (mono(d2)<<32 | p0>>2) picks exactly it.
// launch_bounds(256,4): cap 128 VGPRs — do NOT squeeze the allocator (r4:
// (256,8) forced VGPR=32 and spilled best[]/grp[] to scratch, +600MB HBM).
__global__ void __launch_bounds__(256, 4) fused_kernel(
        const float* __restrict__ mesh, const float* __restrict__ recv,
        float* __restrict__ out, unsigned long long* __restrict__ ws,
        int L, int B, int ntiles) {
    __shared__ unsigned long long wmin[4][RPW];

    const int tid  = threadIdx.x;
    const int lane = tid & 63;
    const int wave = tid >> 6;
    const int rq   = blockIdx.x / NQ;      // receiver quarter 0..3
    const int q0   = blockIdx.x % NQ;      // starting tile phase

    // ---- receiver set into SGPRs (once) ----
    float rx[RPW], ry[RPW], rz[RPW], rsq[RPW];
#pragma unroll
    for (int c = 0; c < RPW; ++c) {
        const int r = rq * RPW + c;
        float x = 0.f, y = 0.f, z = 0.f;
        if (r < B) {                       // uniform branch
            x = recv[r * 3 + 0];
            y = recv[r * 3 + 1];
            z = recv[r * 3 + 2];
        }
        rx[c]  = rfl_f(x);
        ry[c]  = rfl_f(y);
        rz[c]  = rfl_f(z);
        rsq[c] = rfl_f((x * x + y * y) + z * z);   // no FMA (pragma)
    }

    float    best[RPW];
    uint32_t grp[RPW];
#pragma unroll
    for (int c = 0; c < RPW; ++c) { best[c] = FLT_MAX; grp[c] = 0; }

    const bool writer = (rq == 0);         // dedicated writer quarter (r3 pattern)

    for (int t = q0; t < ntiles; t += NQ) {
        const int p0 = (t << 10) + (wave << 8) + (lane << 2);   // lane's 4 points
        float x0, y0, z0, x1, y1, z1, x2, y2, z2, x3, y3, z3;
        float ms0, ms1, ms2, ms3;
        if (p0 + 4 <= L) {
            const float4* __restrict__ m4 = (const float4*)(mesh + (size_t)p0 * 3);
            const float4 fa = m4[0], fb = m4[1], fc = m4[2];
            if (writer) {
                float4* __restrict__ o4 = (float4*)(out + (size_t)p0 * 4);
                o4[0] = make_float4(fa.x, fa.y, fa.z, 0.f);
                o4[1] = make_float4(fa.w, fb.x, fb.y, 0.f);
                o4[2] = make_float4(fb.z, fb.w, fc.x, 0.f);
                o4[3] = make_float4(fc.y, fc.z, fc.w, 0.f);
            }
            x0 = fa.x; y0 = fa.y; z0 = fa.z;
            x1 = fa.w; y1 = fb.x; z1 = fb.y;
            x2 = fb.z; y2 = fb.w; z2 = fc.x;
            x3 = fc.y; y3 = fc.z; z3 = fc.w;
            ms0 = (x0 * x0 + y0 * y0) + z0 * z0;   // matches jnp.sum(m*m): no FMA
            ms1 = (x1 * x1 + y1 * y1) + z1 * z1;
            ms2 = (x2 * x2 + y2 * y2) + z2 * z2;
            ms3 = (x3 * x3 + y3 * y3) + z3 * z3;
        } else {
            float xs[4], ys[4], zs[4], mss[4];
            for (int j = 0; j < 4; ++j) {
                const int p = p0 + j;
                if (p < L) {
                    xs[j] = mesh[(size_t)p * 3 + 0];
                    ys[j] = mesh[(size_t)p * 3 + 1];
                    zs[j] = mesh[(size_t)p * 3 + 2];
                    mss[j] = (xs[j] * xs[j] + ys[j] * ys[j]) + zs[j] * zs[j];
                    if (writer) {
                        out[(size_t)p * 4 + 0] = xs[j];
                        out[(size_t)p * 4 + 1] = ys[j];
                        out[(size_t)p * 4 + 2] = zs[j];
                        out[(size_t)p * 4 + 3] = 0.f;
                    }
                } else {
                    xs[j] = 0.f; ys[j] = 0.f; zs[j] = 0.f;
                    mss[j] = INFINITY;     // d2 = +inf, never selected
                }
            }
            x0 = xs[0]; y0 = ys[0]; z0 = zs[0]; ms0 = mss[0];
            x1 = xs[1]; y1 = ys[1]; z1 = zs[1]; ms1 = mss[1];
            x2 = xs[2]; y2 = ys[2]; z2 = zs[2]; ms2 = mss[2];
            x3 = xs[3]; y3 = ys[3]; z3 = zs[3]; ms3 = mss[3];
        }

        const uint32_t g = (uint32_t)p0 >> 2;   // group id, same for all c
#pragma unroll
        for (int c = 0; c < RPW; ++c) {
            // Eigen gemm K-ascending FMA chain; d2 = fma(-2,cr,ms) + rsq
            float cr0 = fmaf(rz[c], z0, fmaf(ry[c], y0, rx[c] * x0));
            float d0  = fmaf(-2.0f, cr0, ms0) + rsq[c];
            float cr1 = fmaf(rz[c], z1, fmaf(ry[c], y1, rx[c] * x1));
            float d1  = fmaf(-2.0f, cr1, ms1) + rsq[c];
            float cr2 = fmaf(rz[c], z2, fmaf(ry[c], y2, rx[c] * x2));
            float d2v = fmaf(-2.0f, cr2, ms2) + rsq[c];
            float cr3 = fmaf(rz[c], z3, fmaf(ry[c], y3, rx[c] * x3));
            float d3  = fmaf(-2.0f, cr3, ms3) + rsq[c];
            // value-only fold (v_min3 + v_min); ties in VALUE are identical
            // bits, index ties resolved by group ordering + finalize re-eval
            float tl = fminf(fminf(fminf(d0, d1), d2v), d3);
            if (tl < best[c]) { best[c] = tl; grp[c] = g; }   // strict <
        }
    }

    // ---- per-wave butterfly reduce on packed (key|group), tiny LDS fold ----
#pragma unroll
    for (int c = 0; c < RPW; ++c) {
        unsigned long long kk =
            ((unsigned long long)monotone_key(best[c]) << 32) | grp[c];
#pragma unroll
        for (int off = 32; off >= 1; off >>= 1) {
            unsigned long long o = shfl_xor_u64(kk, off);
            if (o < kk) kk = o;
        }
        if (lane == 0) wmin[wave][c] = kk;
    }
    __syncthreads();
    if (tid < RPW) {
        unsigned long long kk = wmin[0][tid];
#pragma unroll
        for (int w = 1; w < 4; ++w) {
            unsigned long long o = wmin[w][tid];
            if (o < kk) kk = o;
        }
        const int r = rq * RPW + tid;
        if (r < B) atomicMin(&ws[r], kk);
    }
}

// Recover exact argmin within the winning 4-point group (bit-identical
// re-evaluation, same TU => same contract-off arithmetic), then scatter
// one-hot 1.0 and emit closest_points.
__global__ void finalize_kernel(
        const float* __restrict__ mesh, const float* __restrict__ recv,
        const unsigned long long* __restrict__ ws,
        float* __restrict__ out, int L, int B) {
    const int r = threadIdx.x;
    if (r >= B) return;
    const unsigned long long key = ws[r];
    const int p0 = (int)(key & 0xFFFFFFFFull) << 2;

    const float rx = recv[r * 3 + 0];
    const float ry = recv[r * 3 + 1];
    const float rz = recv[r * 3 + 2];
    const float rsq = (rx * rx + ry * ry) + rz * rz;   // no FMA (pragma)

    float bestd = FLT_MAX;
    int   bidx  = p0;
    for (int j = 0; j < 4; ++j) {
        const int p = p0 + j;
        float d2;
        if (p < L) {
            const float x = mesh[(size_t)p * 3 + 0];
            const float y = mesh[(size_t)p * 3 + 1];
            const float z = mesh[(size_t)p * 3 + 2];
            const float ms = (x * x + y * y) + z * z;
            const float cr = fmaf(rz, z, fmaf(ry, y, rx * x));
            d2 = fmaf(-2.0f, cr, ms) + rsq;
        } else {
            d2 = INFINITY;
        }
        if (d2 < bestd) { bestd = d2; bidx = p; }   // strict <: first index
    }

    out[(size_t)bidx * 4 + 3] = 1.0f;
    float* cp = out + (size_t)L * 4 + (size_t)r * 3;
    cp[0] = mesh[(size_t)bidx * 3 + 0];
    cp[1] = mesh[(size_t)bidx * 3 + 1];
    cp[2] = mesh[(size_t)bidx * 3 + 2];
}

extern "C" void kernel_launch(void* const* d_in, const int* in_sizes, int n_in,
                              void* d_out, int out_size, void* d_ws, size_t ws_size,
                              hipStream_t stream) {
    const float* mesh = (const float*)d_in[0];
    const float* recv = (const float*)d_in[1];
    float* out = (float*)d_out;
    const int L = in_sizes[0] / 3;
    const int B = in_sizes[1] / 3;   // 64
    unsigned long long* ws = (unsigned long long*)d_ws;

    // init per-receiver packed (key|group) mins to all-ones (max)
    hipMemsetAsync(ws, 0xFF, (size_t)B * sizeof(unsigned long long), stream);

    const int ntiles = (L + 1023) / 1024;
    fused_kernel<<<4 * NQ, 256, 0, stream>>>(mesh, recv, out, ws, L, B, ntiles);

    finalize_kernel<<<1, 64, 0, stream>>>(mesh, recv, ws, out, L, B);
}

// Round 9
// 61.256 us; speedup vs baseline: 1.1198x; 1.1198x over previous
//
#include <hip/hip_runtime.h>
#include <cfloat>
#include <math.h>
#include <stdint.h>

// Match XLA-CPU f32 arithmetic exactly: no implicit contraction anywhere;
// FMA only where written explicitly (Eigen-gemm-style cross product).
#pragma clang fp contract(off)

#define RPW 16       // receivers per block (quarter of B=64)
#define NQ  256      // tile phases; grid = 4*NQ = 1024 (r3/r8 geometry: best.
                     // r5/r6 showed bigger grids break L2 co-walking.)
#define PPL 8        // points per lane per tile iteration
#define TILESZ (256 * PPL)   // 2048 points per tile

__device__ __forceinline__ uint32_t monotone_key(float f) {
    uint32_t u = __float_as_uint(f);
    return (u & 0x80000000u) ? ~u : (u | 0x80000000u);
}

// force a wave-uniform float into an SGPR
__device__ __forceinline__ float rfl_f(float x) {
    return __uint_as_float((uint32_t)__builtin_amdgcn_readfirstlane((int)__float_as_uint(x)));
}

__device__ __forceinline__ unsigned long long shfl_xor_u64(unsigned long long v, int m) {
    uint32_t lo = (uint32_t)v, hi = (uint32_t)(v >> 32);
    lo = (uint32_t)__shfl_xor((int)lo, m, 64);
    hi = (uint32_t)__shfl_xor((int)hi, m, 64);
    return ((unsigned long long)hi << 32) | lo;
}

// lane = point-group; 16 receivers in SGPRs -> pure-VALU inner loop at
// 5.0 ops/pair: v_j = fma(-2, cr_j, ms_j) (4 ops), min-tree fold (4),
// + rsq once per group (1), strict-< group update (3) over 8 pairs.
// EXACTNESS of the rsq hoist: round() is monotone nondecreasing, so
//   min_j round(v_j + rsq) == round(min_j v_j + rsq)
// bit-for-bit; d2g equals the reference's min d2 over the group. Group
// update compares in d2-space with strict <, groups ascend within a block,
// and the packed u64 (mono(d2)<<32 | g) atomicMin resolves cross-block ties
// toward the lowest group => the reference's first-occurrence argmin lies in
// the winning group; finalize re-evaluates its 8 points bit-identically.
// launch_bounds(256,4): cap 128 VGPRs — do NOT squeeze the allocator (r4:
// (256,8) forced VGPR=32 and spilled best[]/grp[] to scratch, +600MB HBM).
__global__ void __launch_bounds__(256, 4) fused_kernel(
        const float* __restrict__ mesh, const float* __restrict__ recv,
        float* __restrict__ out, unsigned long long* __restrict__ ws,
        int L, int B, int ntiles) {
    __shared__ unsigned long long wmin[4][RPW];

    const int tid  = threadIdx.x;
    const int lane = tid & 63;
    const int wave = tid >> 6;
    const int rq   = blockIdx.x / NQ;      // receiver quarter 0..3
    const int q0   = blockIdx.x % NQ;      // starting tile phase

    // ---- receiver set into SGPRs (once) ----
    float rx[RPW], ry[RPW], rz[RPW], rsq[RPW];
#pragma unroll
    for (int c = 0; c < RPW; ++c) {
        const int r = rq * RPW + c;
        float x = 0.f, y = 0.f, z = 0.f;
        if (r < B) {                       // uniform branch
            x = recv[r * 3 + 0];
            y = recv[r * 3 + 1];
            z = recv[r * 3 + 2];
        }
        rx[c]  = rfl_f(x);
        ry[c]  = rfl_f(y);
        rz[c]  = rfl_f(z);
        rsq[c] = rfl_f((x * x + y * y) + z * z);   // no FMA (pragma)
    }

    float    best[RPW];
    uint32_t grp[RPW];
#pragma unroll
    for (int c = 0; c < RPW; ++c) { best[c] = FLT_MAX; grp[c] = 0; }

    const bool writer = (rq == 0);         // dedicated writer quarter

    for (int t = q0; t < ntiles; t += NQ) {
        const int p0 = t * TILESZ + (wave << 9) + (lane << 3);  // lane's 8 points
        float xs[PPL], ys[PPL], zs[PPL], ms[PPL];
        if (p0 + PPL <= L) {
            const float4* __restrict__ m4 = (const float4*)(mesh + (size_t)p0 * 3);
            const float4 fa = m4[0], fb = m4[1], fc = m4[2];
            const float4 fd = m4[3], fe = m4[4], ff = m4[5];
            if (writer) {
                float4* __restrict__ o4 = (float4*)(out + (size_t)p0 * 4);
                o4[0] = make_float4(fa.x, fa.y, fa.z, 0.f);
                o4[1] = make_float4(fa.w, fb.x, fb.y, 0.f);
                o4[2] = make_float4(fb.z, fb.w, fc.x, 0.f);
                o4[3] = make_float4(fc.y, fc.z, fc.w, 0.f);
                o4[4] = make_float4(fd.x, fd.y, fd.z, 0.f);
                o4[5] = make_float4(fd.w, fe.x, fe.y, 0.f);
                o4[6] = make_float4(fe.z, fe.w, ff.x, 0.f);
                o4[7] = make_float4(ff.y, ff.z, ff.w, 0.f);
            }
            xs[0] = fa.x; ys[0] = fa.y; zs[0] = fa.z;
            xs[1] = fa.w; ys[1] = fb.x; zs[1] = fb.y;
            xs[2] = fb.z; ys[2] = fb.w; zs[2] = fc.x;
            xs[3] = fc.y; ys[3] = fc.z; zs[3] = fc.w;
            xs[4] = fd.x; ys[4] = fd.y; zs[4] = fd.z;
            xs[5] = fd.w; ys[5] = fe.x; zs[5] = fe.y;
            xs[6] = fe.z; ys[6] = fe.w; zs[6] = ff.x;
            xs[7] = ff.y; ys[7] = ff.z; zs[7] = ff.w;
#pragma unroll
            for (int j = 0; j < PPL; ++j)
                ms[j] = (xs[j] * xs[j] + ys[j] * ys[j]) + zs[j] * zs[j];  // no FMA
        } else {
#pragma unroll
            for (int j = 0; j < PPL; ++j) {
                const int p = p0 + j;
                if (p < L) {
                    xs[j] = mesh[(size_t)p * 3 + 0];
                    ys[j] = mesh[(size_t)p * 3 + 1];
                    zs[j] = mesh[(size_t)p * 3 + 2];
                    ms[j] = (xs[j] * xs[j] + ys[j] * ys[j]) + zs[j] * zs[j];
                    if (writer) {
                        out[(size_t)p * 4 + 0] = xs[j];
                        out[(size_t)p * 4 + 1] = ys[j];
                        out[(size_t)p * 4 + 2] = zs[j];
                        out[(size_t)p * 4 + 3] = 0.f;
                    }
                } else {
                    xs[j] = 0.f; ys[j] = 0.f; zs[j] = 0.f;
                    ms[j] = INFINITY;      // v = +inf, never selected
                }
            }
        }

        const uint32_t g = (uint32_t)(p0 >> 3);   // 8-point group id
#pragma unroll
        for (int c = 0; c < RPW; ++c) {
            float v[PPL];
#pragma unroll
            for (int j = 0; j < PPL; ++j) {
                // Eigen gemm K-ascending chain; v = fma(-2, cr, ms) (4 ops)
                float cr = fmaf(rz[c], zs[j], fmaf(ry[c], ys[j], rx[c] * xs[j]));
                v[j] = fmaf(-2.0f, cr, ms[j]);
            }
            // min3-shaped fold: 4 instructions for 8 values
            float a  = fminf(fminf(v[0], v[1]), v[2]);
            float b  = fminf(fminf(v[3], v[4]), v[5]);
            float cc = fminf(v[6], v[7]);
            float tl = fminf(fminf(a, b), cc);
            float d2g = tl + rsq[c];       // == min_j d2_j bit-exact (monotone)
            if (d2g < best[c]) { best[c] = d2g; grp[c] = g; }   // strict <
        }
    }

    // ---- per-wave butterfly reduce on packed (key|group), tiny LDS fold ----
#pragma unroll
    for (int c = 0; c < RPW; ++c) {
        unsigned long long kk =
            ((unsigned long long)monotone_key(best[c]) << 32) | grp[c];
#pragma unroll
        for (int off = 32; off >= 1; off >>= 1) {
            unsigned long long o = shfl_xor_u64(kk, off);
            if (o < kk) kk = o;
        }
        if (lane == 0) wmin[wave][c] = kk;
    }
    __syncthreads();
    if (tid < RPW) {
        unsigned long long kk = wmin[0][tid];
#pragma unroll
        for (int w = 1; w < 4; ++w) {
            unsigned long long o = wmin[w][tid];
            if (o < kk) kk = o;
        }
        const int r = rq * RPW + tid;
        if (r < B) atomicMin(&ws[r], kk);
    }
}

// Recover exact argmin within the winning 8-point group (bit-identical
// re-evaluation, same TU => same contract-off arithmetic), then scatter
// one-hot 1.0 and emit closest_points.
__global__ void finalize_kernel(
        const float* __restrict__ mesh, const float* __restrict__ recv,
        const unsigned long long* __restrict__ ws,
        float* __restrict__ out, int L, int B) {
    const int r = threadIdx.x;
    if (r >= B) return;
    const unsigned long long key = ws[r];
    const int p0 = (int)(key & 0xFFFFFFFFull) << 3;

    const float rx = recv[r * 3 + 0];
    const float ry = recv[r * 3 + 1];
    const float rz = recv[r * 3 + 2];
    const float rsq = (rx * rx + ry * ry) + rz * rz;   // no FMA (pragma)

    float bestd = FLT_MAX;
    int   bidx  = p0;
    for (int j = 0; j < 8; ++j) {
        const int p = p0 + j;
        float d2;
        if (p < L) {
            const float x = mesh[(size_t)p * 3 + 0];
            const float y = mesh[(size_t)p * 3 + 1];
            const float z = mesh[(size_t)p * 3 + 2];
            const float ms = (x * x + y * y) + z * z;
            const float cr = fmaf(rz, z, fmaf(ry, y, rx * x));
            d2 = fmaf(-2.0f, cr, ms) + rsq;
        } else {
            d2 = INFINITY;
        }
        if (d2 < bestd) { bestd = d2; bidx = p; }   // strict <: first index
    }

    out[(size_t)bidx * 4 + 3] = 1.0f;
    float* cp = out + (size_t)L * 4 + (size_t)r * 3;
    cp[0] = mesh[(size_t)bidx * 3 + 0];
    cp[1] = mesh[(size_t)bidx * 3 + 1];
    cp[2] = mesh[(size_t)bidx * 3 + 2];
}

extern "C" void kernel_launch(void* const* d_in, const int* in_sizes, int n_in,
                              void* d_out, int out_size, void* d_ws, size_t ws_size,
                              hipStream_t stream) {
    const float* mesh = (const float*)d_in[0];
    const float* recv = (const float*)d_in[1];
    float* out = (float*)d_out;
    const int L = in_sizes[0] / 3;
    const int B = in_sizes[1] / 3;   // 64
    unsigned long long* ws = (unsigned long long*)d_ws;

    // init per-receiver packed (key|group) mins to all-ones (max)
    hipMemsetAsync(ws, 0xFF, (size_t)B * sizeof(unsigned long long), stream);

    const int ntiles = (L + TILESZ - 1) / TILESZ;
    fused_kernel<<<4 * NQ, 256, 0, stream>>>(mesh, recv, out, ws, L, B, ntiles);

    finalize_kernel<<<1, 64, 0, stream>>>(mesh, recv, ws, out, L, B);
}

// Round 10
// 58.055 us; speedup vs baseline: 1.1815x; 1.0551x over previous
//
#include <hip/hip_runtime.h>
#include <cfloat>
#include <math.h>
#include <stdint.h>

// Match XLA-CPU f32 arithmetic exactly: no implicit contraction anywhere;
// FMA only where written explicitly (Eigen-gemm-style cross product).
// v_pk_fma_f32 / v_pk_mul_f32 / v_pk_add_f32 are IEEE-identical per
// component to their scalar forms, so packing does not change results.
#pragma clang fp contract(off)

typedef float v2f __attribute__((ext_vector_type(2)));

#define RPW 16       // receivers per block (quarter of B=64)
#define NQ  256      // tile phases; grid = 4*NQ = 1024 (r3/r8 geometry: best.
                     // r5/r6 showed bigger grids break L2 co-walking.)
#define PPL 8        // points per lane per tile iteration
#define TILESZ (256 * PPL)   // 2048 points per tile

__device__ __forceinline__ uint32_t monotone_key(float f) {
    uint32_t u = __float_as_uint(f);
    return (u & 0x80000000u) ? ~u : (u | 0x80000000u);
}

// force a wave-uniform float into an SGPR
__device__ __forceinline__ float rfl_f(float x) {
    return __uint_as_float((uint32_t)__builtin_amdgcn_readfirstlane((int)__float_as_uint(x)));
}

__device__ __forceinline__ unsigned long long shfl_xor_u64(unsigned long long v, int m) {
    uint32_t lo = (uint32_t)v, hi = (uint32_t)(v >> 32);
    lo = (uint32_t)__shfl_xor((int)lo, m, 64);
    hi = (uint32_t)__shfl_xor((int)hi, m, 64);
    return ((unsigned long long)hi << 32) | lo;
}

__device__ __forceinline__ v2f sp(float s) { return (v2f){s, s}; }
__device__ __forceinline__ v2f pkfma(v2f a, v2f b, v2f c) {
    return __builtin_elementwise_fma(a, b, c);   // -> v_pk_fma_f32 (2x f32/instr)
}

// lane = 8-point group; 16 receivers in SGPRs; inner loop in PACKED f32:
// per point-pair: pk_mul + 2x pk_fma (Eigen K-ascending cr chain) + pk_fma
// (-2*cr+ms), then scalar min-fold of the 8 components, + rsq once (bit-
// exact hoist: round() monotone => min_j round(v_j+r) == round(min_j v_j + r)),
// one strict-< group update. Exact index recovered in finalize by
// re-evaluating the winning 8-point group with the byte-identical scalar
// chain. Software pipeline: consume tile t's regs -> issue t+NQ's loads ->
// ~400-instr eval hides the load latency.
// launch_bounds(256,4): cap 128 VGPRs — do NOT squeeze the allocator (r4:
// (256,8) forced VGPR=32 and spilled best[]/grp[] to scratch, +600MB HBM).
__global__ void __launch_bounds__(256, 4) fused_kernel(
        const float* __restrict__ mesh, const float* __restrict__ recv,
        float* __restrict__ out, unsigned long long* __restrict__ ws,
        int L, int B, int ntiles) {
    __shared__ unsigned long long wmin[4][RPW];

    const int tid  = threadIdx.x;
    const int lane = tid & 63;
    const int wave = tid >> 6;
    const int rq   = blockIdx.x / NQ;      // receiver quarter 0..3
    const int q0   = blockIdx.x % NQ;      // starting tile phase

    // ---- receiver set into SGPRs (once) ----
    float rx[RPW], ry[RPW], rz[RPW], rsq[RPW];
#pragma unroll
    for (int c = 0; c < RPW; ++c) {
        const int r = rq * RPW + c;
        float x = 0.f, y = 0.f, z = 0.f;
        if (r < B) {                       // uniform branch
            x = recv[r * 3 + 0];
            y = recv[r * 3 + 1];
            z = recv[r * 3 + 2];
        }
        rx[c]  = rfl_f(x);
        ry[c]  = rfl_f(y);
        rz[c]  = rfl_f(z);
        rsq[c] = rfl_f((x * x + y * y) + z * z);   // no FMA (pragma)
    }

    float    best[RPW];
    uint32_t grp[RPW];
#pragma unroll
    for (int c = 0; c < RPW; ++c) { best[c] = FLT_MAX; grp[c] = 0; }

    const bool writer = (rq == 0);         // dedicated writer quarter

    // ---- prologue: load first tile's 6 float4 (full lanes only) ----
    float4 nb0, nb1, nb2, nb3, nb4, nb5;
    int  t  = q0;
    int  p0 = t * TILESZ + (wave << 9) + (lane << 3);
    bool curFull = (t < ntiles) && (p0 + PPL <= L);
    if (curFull) {
        const float4* __restrict__ m4 = (const float4*)(mesh + (size_t)p0 * 3);
        nb0 = m4[0]; nb1 = m4[1]; nb2 = m4[2];
        nb3 = m4[3]; nb4 = m4[4]; nb5 = m4[5];
    }

    while (t < ntiles) {
        v2f x2[4], y2[4], z2[4], ms2[4];
        if (curFull) {
            // consume prefetch buffer: pack point-pairs (2j, 2j+1)
            x2[0] = (v2f){nb0.x, nb0.w}; y2[0] = (v2f){nb0.y, nb1.x}; z2[0] = (v2f){nb0.z, nb1.y};
            x2[1] = (v2f){nb1.z, nb2.y}; y2[1] = (v2f){nb1.w, nb2.z}; z2[1] = (v2f){nb2.x, nb2.w};
            x2[2] = (v2f){nb3.x, nb3.w}; y2[2] = (v2f){nb3.y, nb4.x}; z2[2] = (v2f){nb3.z, nb4.y};
            x2[3] = (v2f){nb4.z, nb5.y}; y2[3] = (v2f){nb4.w, nb5.z}; z2[3] = (v2f){nb5.x, nb5.w};
#pragma unroll
            for (int j = 0; j < 4; ++j)
                ms2[j] = (x2[j] * x2[j] + y2[j] * y2[j]) + z2[j] * z2[j];  // pk mul/add, no FMA
            if (writer) {
                float4* __restrict__ o4 = (float4*)(out + (size_t)p0 * 4);
                o4[0] = make_float4(x2[0].x, y2[0].x, z2[0].x, 0.f);
                o4[1] = make_float4(x2[0].y, y2[0].y, z2[0].y, 0.f);
                o4[2] = make_float4(x2[1].x, y2[1].x, z2[1].x, 0.f);
                o4[3] = make_float4(x2[1].y, y2[1].y, z2[1].y, 0.f);
                o4[4] = make_float4(x2[2].x, y2[2].x, z2[2].x, 0.f);
                o4[5] = make_float4(x2[2].y, y2[2].y, z2[2].y, 0.f);
                o4[6] = make_float4(x2[3].x, y2[3].x, z2[3].x, 0.f);
                o4[7] = make_float4(x2[3].y, y2[3].y, z2[3].y, 0.f);
            }
        } else {
            float xx[PPL], yy[PPL], zz[PPL], mm[PPL];
#pragma unroll
            for (int j = 0; j < PPL; ++j) {
                const int p = p0 + j;
                if (p < L) {
                    xx[j] = mesh[(size_t)p * 3 + 0];
                    yy[j] = mesh[(size_t)p * 3 + 1];
                    zz[j] = mesh[(size_t)p * 3 + 2];
                    mm[j] = (xx[j] * xx[j] + yy[j] * yy[j]) + zz[j] * zz[j];
                    if (writer) {
                        out[(size_t)p * 4 + 0] = xx[j];
                        out[(size_t)p * 4 + 1] = yy[j];
                        out[(size_t)p * 4 + 2] = zz[j];
                        out[(size_t)p * 4 + 3] = 0.f;
                    }
                } else {
                    xx[j] = 0.f; yy[j] = 0.f; zz[j] = 0.f;
                    mm[j] = INFINITY;      // v = +inf, never selected
                }
            }
#pragma unroll
            for (int j = 0; j < 4; ++j) {
                x2[j]  = (v2f){xx[2 * j], xx[2 * j + 1]};
                y2[j]  = (v2f){yy[2 * j], yy[2 * j + 1]};
                z2[j]  = (v2f){zz[2 * j], zz[2 * j + 1]};
                ms2[j] = (v2f){mm[2 * j], mm[2 * j + 1]};
            }
        }

        // ---- prefetch next tile (nb is dead now); eval below hides latency
        const int  tn  = t + NQ;
        const int  pn0 = tn * TILESZ + (wave << 9) + (lane << 3);
        const bool nextFull = (tn < ntiles) && (pn0 + PPL <= L);
        if (nextFull) {
            const float4* __restrict__ m4 = (const float4*)(mesh + (size_t)pn0 * 3);
            nb0 = m4[0]; nb1 = m4[1]; nb2 = m4[2];
            nb3 = m4[3]; nb4 = m4[4]; nb5 = m4[5];
        }

        // ---- packed eval: 8 points x 16 receivers ----
        const uint32_t g = (uint32_t)(p0 >> 3);   // 8-point group id
#pragma unroll
        for (int c = 0; c < RPW; ++c) {
            // per pair: cr = pk_fma(rz, z2, pk_fma(ry, y2, pk_mul(rx, x2)));
            //           v  = pk_fma(-2, cr, ms2)   [Eigen K-ascending chain]
            v2f vA = pkfma(sp(-2.0f),
                           pkfma(sp(rz[c]), z2[0], pkfma(sp(ry[c]), y2[0], sp(rx[c]) * x2[0])),
                           ms2[0]);
            v2f vB = pkfma(sp(-2.0f),
                           pkfma(sp(rz[c]), z2[1], pkfma(sp(ry[c]), y2[1], sp(rx[c]) * x2[1])),
                           ms2[1]);
            v2f vC = pkfma(sp(-2.0f),
                           pkfma(sp(rz[c]), z2[2], pkfma(sp(ry[c]), y2[2], sp(rx[c]) * x2[2])),
                           ms2[2]);
            v2f vD = pkfma(sp(-2.0f),
                           pkfma(sp(rz[c]), z2[3], pkfma(sp(ry[c]), y2[3], sp(rx[c]) * x2[3])),
                           ms2[3]);
            // scalar min-tree over the 8 components (exact: min is assoc/comm)
            float a  = fminf(fminf(vA.x, vA.y), vB.x);
            float b  = fminf(fminf(vB.y, vC.x), vC.y);
            float cc = fminf(vD.x, vD.y);
            float tl = fminf(fminf(a, b), cc);
            float d2g = tl + rsq[c];       // == min_j d2_j bit-exact (monotone)
            if (d2g < best[c]) { best[c] = d2g; grp[c] = g; }   // strict <
        }

        t = tn; p0 = pn0; curFull = nextFull;
    }

    // ---- per-wave butterfly reduce on packed (key|group), tiny LDS fold ----
#pragma unroll
    for (int c = 0; c < RPW; ++c) {
        unsigned long long kk =
            ((unsigned long long)monotone_key(best[c]) << 32) | grp[c];
#pragma unroll
        for (int off = 32; off >= 1; off >>= 1) {
            unsigned long long o = shfl_xor_u64(kk, off);
            if (o < kk) kk = o;
        }
        if (lane == 0) wmin[wave][c] = kk;
    }
    __syncthreads();
    if (tid < RPW) {
        unsigned long long kk = wmin[0][tid];
#pragma unroll
        for (int w = 1; w < 4; ++w) {
            unsigned long long o = wmin[w][tid];
            if (o < kk) kk = o;
        }
        const int r = rq * RPW + tid;
        if (r < B) atomicMin(&ws[r], kk);
    }
}

// Recover exact argmin within the winning 8-point group (bit-identical
// re-evaluation, same TU => same contract-off arithmetic), then scatter
// one-hot 1.0 and emit closest_points.
__global__ void finalize_kernel(
        const float* __restrict__ mesh, const float* __restrict__ recv,
        const unsigned long long* __restrict__ ws,
        float* __restrict__ out, int L, int B) {
    const int r = threadIdx.x;
    if (r >= B) return;
    const unsigned long long key = ws[r];
    const int p0 = (int)(key & 0xFFFFFFFFull) << 3;

    const float rx = recv[r * 3 + 0];
    const float ry = recv[r * 3 + 1];
    const float rz = recv[r * 3 + 2];
    const float rsq = (rx * rx + ry * ry) + rz * rz;   // no FMA (pragma)

    float bestd = FLT_MAX;
    int   bidx  = p0;
    for (int j = 0; j < 8; ++j) {
        const int p = p0 + j;
        float d2;
        if (p < L) {
            const float x = mesh[(size_t)p * 3 + 0];
            const float y = mesh[(size_t)p * 3 + 1];
            const float z = mesh[(size_t)p * 3 + 2];
            const float ms = (x * x + y * y) + z * z;
            const float cr = fmaf(rz, z, fmaf(ry, y, rx * x));
            d2 = fmaf(-2.0f, cr, ms) + rsq;
        } else {
            d2 = INFINITY;
        }
        if (d2 < bestd) { bestd = d2; bidx = p; }   // strict <: first index
    }

    out[(size_t)bidx * 4 + 3] = 1.0f;
    float* cp = out + (size_t)L * 4 + (size_t)r * 3;
    cp[0] = mesh[(size_t)bidx * 3 + 0];
    cp[1] = mesh[(size_t)bidx * 3 + 1];
    cp[2] = mesh[(size_t)bidx * 3 + 2];
}

extern "C" void kernel_launch(void* const* d_in, const int* in_sizes, int n_in,
                              void* d_out, int out_size, void* d_ws, size_t ws_size,
                              hipStream_t stream) {
    const float* mesh = (const float*)d_in[0];
    const float* recv = (const float*)d_in[1];
    float* out = (float*)d_out;
    const int L = in_sizes[0] / 3;
    const int B = in_sizes[1] / 3;   // 64
    unsigned long long* ws = (unsigned long long*)d_ws;

    // init per-receiver packed (key|group) mins to all-ones (max)
    hipMemsetAsync(ws, 0xFF, (size_t)B * sizeof(unsigned long long), stream);

    const int ntiles = (L + TILESZ - 1) / TILESZ;
    fused_kernel<<<4 * NQ, 256, 0, stream>>>(mesh, recv, out, ws, L, B, ntiles);

    finalize_kernel<<<1, 64, 0, stream>>>(mesh, recv, ws, out, L, B);
}